// Round 1
// baseline (43354.639 us; speedup 1.0000x reference)
//
#include <hip/hip_runtime.h>
#include <math.h>

#define B_ 64
#define T_ 512

// ---------------------------------------------------------------------------
// GEMM: C[M,N] = (A[M,K] * mask[row/T_, :]) @ W[K,N] + bias[N]
// fp32, 64x64 tile, TK=32, 256 threads, 4x4 microtile per thread.
// ---------------------------------------------------------------------------
__global__ __launch_bounds__(256) void gemm_mask_kernel(
    const float* __restrict__ A, const float* __restrict__ W,
    const float* __restrict__ bias, const float* __restrict__ mask,
    float* __restrict__ C, int M, int N, int K)
{
    const int TM = 64, TN = 64, TK = 32;
    __shared__ __align__(16) float As[TK][68];   // transposed A tile [k][m], pad 68
    __shared__ __align__(16) float Bs[TK][68];   // B tile [k][n], pad 68

    const int tid = threadIdx.x;
    const int bn = blockIdx.x;      // N tile
    const int bm = blockIdx.y;      // M tile
    const int row0 = bm * TM;
    const int b = row0 / T_;        // batch index (uniform: T_ % TM == 0)

    const int ty = tid >> 4;        // 0..15
    const int tx = tid & 15;        // 0..15
    const int m0 = ty * 4;
    const int n0 = tx * 4;

    float acc[4][4];
#pragma unroll
    for (int i = 0; i < 4; i++)
#pragma unroll
        for (int j = 0; j < 4; j++) acc[i][j] = 0.f;

    for (int kk = 0; kk < K; kk += TK) {
        // stage A (64 rows x 32 k), masked, transposed into As[k][m]
        {
            const int r = tid >> 3;            // 0..31
            const int kq = (tid & 7) << 2;     // 0,4,...,28
            const float4 mv = *(const float4*)(mask + (size_t)b * K + kk + kq);
#pragma unroll
            for (int rr = 0; rr < 2; rr++) {
                const int r2 = r + rr * 32;
                const float4 av = *(const float4*)(A + (size_t)(row0 + r2) * K + kk + kq);
                As[kq + 0][r2] = av.x * mv.x;
                As[kq + 1][r2] = av.y * mv.y;
                As[kq + 2][r2] = av.z * mv.z;
                As[kq + 3][r2] = av.w * mv.w;
            }
        }
        // stage B (32 k x 64 n)
        {
            const int kr = tid >> 4;           // 0..15
            const int nq = (tid & 15) << 2;    // 0..60
#pragma unroll
            for (int rr = 0; rr < 2; rr++) {
                const int k2 = kr + rr * 16;
                const float4 bv = *(const float4*)(W + (size_t)(kk + k2) * N + bn * TN + nq);
                *(float4*)&Bs[k2][nq] = bv;
            }
        }
        __syncthreads();

#pragma unroll
        for (int k = 0; k < TK; k++) {
            const float4 av = *(const float4*)&As[k][m0];
            const float4 bv = *(const float4*)&Bs[k][n0];
            acc[0][0] += av.x * bv.x; acc[0][1] += av.x * bv.y; acc[0][2] += av.x * bv.z; acc[0][3] += av.x * bv.w;
            acc[1][0] += av.y * bv.x; acc[1][1] += av.y * bv.y; acc[1][2] += av.y * bv.z; acc[1][3] += av.y * bv.w;
            acc[2][0] += av.z * bv.x; acc[2][1] += av.z * bv.y; acc[2][2] += av.z * bv.z; acc[2][3] += av.z * bv.w;
            acc[3][0] += av.w * bv.x; acc[3][1] += av.w * bv.y; acc[3][2] += av.w * bv.z; acc[3][3] += av.w * bv.w;
        }
        __syncthreads();
    }

    const float4 bv = *(const float4*)(bias + bn * TN + n0);
#pragma unroll
    for (int i = 0; i < 4; i++) {
        float4 v;
        v.x = acc[i][0] + bv.x;
        v.y = acc[i][1] + bv.y;
        v.z = acc[i][2] + bv.z;
        v.w = acc[i][3] + bv.w;
        *(float4*)&C[(size_t)(row0 + m0 + i) * N + bn * TN + n0] = v;
    }
}

// ---------------------------------------------------------------------------
// LSTM recurrence. One workgroup per batch element; thread g owns gate column
// g and keeps U[:,g] (HN floats) in registers. h broadcast through LDS.
// Gate order (Keras): i, f, g(cell), o. Activations: sig, sig, tanh, sig.
// ---------------------------------------------------------------------------
__device__ __forceinline__ float fast_sigmoid(float z) {
    return 1.f / (1.f + __expf(-z));
}
__device__ __forceinline__ float fast_tanh(float z) {
    // 1 - 2/(e^{2z}+1); overflow-safe (exp->inf => 1, exp->0 => -1)
    const float e = __expf(2.f * z);
    return 1.f - 2.f / (e + 1.f);
}

template <int HN>
__global__ __launch_bounds__(4 * HN) void lstm_rec_kernel(
    const float* __restrict__ xz,   // [B, T, 4*HN]
    const float* __restrict__ U,    // [HN, 4*HN]
    float* __restrict__ hout,       // [B, T, HN] or nullptr
    float* __restrict__ out_last)   // [B, HN] or nullptr
{
    const int GATES = 4 * HN;
    __shared__ __align__(16) float h_sh[HN];
    __shared__ __align__(16) float act_sh[GATES];

    const int g = threadIdx.x;
    const int b = blockIdx.x;

    // resident weight column U[:, g]
    float u[HN];
#pragma unroll
    for (int k = 0; k < HN; k++) u[k] = U[(size_t)k * GATES + g];

    if (g < HN) h_sh[g] = 0.f;
    float c = 0.f;
    __syncthreads();

    const float* xzb = xz + (size_t)b * T_ * GATES;
    // wave-uniform gate class: sigmoid except range [2*HN, 3*HN) -> tanh
    const bool is_tanh_gate = (g >= 2 * HN) && (g < 3 * HN);

    for (int t = 0; t < T_; t++) {
        float z = xzb[(size_t)t * GATES + g];
#pragma unroll
        for (int k4 = 0; k4 < HN; k4 += 4) {
            const float4 h4 = *(const float4*)&h_sh[k4];
            z += h4.x * u[k4 + 0];
            z += h4.y * u[k4 + 1];
            z += h4.z * u[k4 + 2];
            z += h4.w * u[k4 + 3];
        }
        const float a = is_tanh_gate ? fast_tanh(z) : fast_sigmoid(z);
        act_sh[g] = a;
        __syncthreads();

        if (g < HN) {
            const float i_g = act_sh[g];
            const float f_g = act_sh[HN + g];
            const float g_g = act_sh[2 * HN + g];
            const float o_g = act_sh[3 * HN + g];
            c = f_g * c + i_g * g_g;
            const float h = o_g * fast_tanh(c);
            h_sh[g] = h;
            if (hout) hout[((size_t)b * T_ + t) * HN + g] = h;
            if (out_last && t == T_ - 1) out_last[(size_t)b * HN + g] = h;
        }
        __syncthreads();
    }
}

// ---------------------------------------------------------------------------
// Launch
// ---------------------------------------------------------------------------
extern "C" void kernel_launch(void* const* d_in, const int* in_sizes, int n_in,
                              void* d_out, int out_size, void* d_ws, size_t ws_size,
                              hipStream_t stream)
{
    const float* x  = (const float*)d_in[0];
    const float* W0 = (const float*)d_in[1];
    const float* U0 = (const float*)d_in[2];
    const float* b0 = (const float*)d_in[3];
    const float* W1 = (const float*)d_in[4];
    const float* U1 = (const float*)d_in[5];
    const float* b1 = (const float*)d_in[6];
    const float* W2 = (const float*)d_in[7];
    const float* U2 = (const float*)d_in[8];
    const float* b2 = (const float*)d_in[9];
    const float* m0 = (const float*)d_in[10];
    const float* m1 = (const float*)d_in[11];
    const float* m2 = (const float*)d_in[12];
    float* out = (float*)d_out;

    // workspace layout (fp32):
    //   xz : 64*512*1024 floats = 134217728 B (reused by all 3 layers)
    //   h0 : 64*512*256 floats  =  33554432 B
    //   h1 : 64*512*256 floats  =  33554432 B
    float* xz = (float*)d_ws;
    float* h0 = (float*)((char*)d_ws + 134217728);
    float* h1 = (float*)((char*)d_ws + 134217728 + 33554432);

    const int M = B_ * T_;  // 32768

    // Layer 0: xz = (x*m0) @ W0 + b0 ; recurrence H=256
    gemm_mask_kernel<<<dim3(1024 / 64, M / 64), 256, 0, stream>>>(x, W0, b0, m0, xz, M, 1024, 128);
    lstm_rec_kernel<256><<<64, 1024, 0, stream>>>(xz, U0, h0, nullptr);

    // Layer 1: xz = (h0*m1) @ W1 + b1 ; recurrence H=256
    gemm_mask_kernel<<<dim3(1024 / 64, M / 64), 256, 0, stream>>>(h0, W1, b1, m1, xz, M, 1024, 256);
    lstm_rec_kernel<256><<<64, 1024, 0, stream>>>(xz, U1, h1, nullptr);

    // Layer 2: xz = (h1*m2) @ W2 + b2 ; recurrence H=128, emit last h only
    gemm_mask_kernel<<<dim3(512 / 64, M / 64), 256, 0, stream>>>(h1, W2, b2, m2, xz, M, 512, 256);
    lstm_rec_kernel<128><<<64, 512, 0, stream>>>(xz, U2, nullptr, out);
}

// Round 2
// 16399.954 us; speedup vs baseline: 2.6436x; 2.6436x over previous
//
#include <hip/hip_runtime.h>
#include <math.h>

#define B_ 64
#define T_ 512

// ---------------------------------------------------------------------------
// GEMM: C[M,N] = (A[M,K] * mask[row/T_, :]) @ W[K,N] + bias[N]
// fp32, 64x64 tile, TK=32, 256 threads, 4x4 microtile per thread.
// ---------------------------------------------------------------------------
__global__ __launch_bounds__(256) void gemm_mask_kernel(
    const float* __restrict__ A, const float* __restrict__ W,
    const float* __restrict__ bias, const float* __restrict__ mask,
    float* __restrict__ C, int M, int N, int K)
{
    const int TM = 64, TN = 64, TK = 32;
    __shared__ __align__(16) float As[TK][68];
    __shared__ __align__(16) float Bs[TK][68];

    const int tid = threadIdx.x;
    const int bn = blockIdx.x;
    const int bm = blockIdx.y;
    const int row0 = bm * TM;
    const int b = row0 / T_;

    const int ty = tid >> 4;
    const int tx = tid & 15;
    const int m0 = ty * 4;
    const int n0 = tx * 4;

    float acc[4][4];
#pragma unroll
    for (int i = 0; i < 4; i++)
#pragma unroll
        for (int j = 0; j < 4; j++) acc[i][j] = 0.f;

    for (int kk = 0; kk < K; kk += TK) {
        {
            const int r = tid >> 3;
            const int kq = (tid & 7) << 2;
            const float4 mv = *(const float4*)(mask + (size_t)b * K + kk + kq);
#pragma unroll
            for (int rr = 0; rr < 2; rr++) {
                const int r2 = r + rr * 32;
                const float4 av = *(const float4*)(A + (size_t)(row0 + r2) * K + kk + kq);
                As[kq + 0][r2] = av.x * mv.x;
                As[kq + 1][r2] = av.y * mv.y;
                As[kq + 2][r2] = av.z * mv.z;
                As[kq + 3][r2] = av.w * mv.w;
            }
        }
        {
            const int kr = tid >> 4;
            const int nq = (tid & 15) << 2;
#pragma unroll
            for (int rr = 0; rr < 2; rr++) {
                const int k2 = kr + rr * 16;
                const float4 bv = *(const float4*)(W + (size_t)(kk + k2) * N + bn * TN + nq);
                *(float4*)&Bs[k2][nq] = bv;
            }
        }
        __syncthreads();

#pragma unroll
        for (int k = 0; k < TK; k++) {
            const float4 av = *(const float4*)&As[k][m0];
            const float4 bv = *(const float4*)&Bs[k][n0];
            acc[0][0] += av.x * bv.x; acc[0][1] += av.x * bv.y; acc[0][2] += av.x * bv.z; acc[0][3] += av.x * bv.w;
            acc[1][0] += av.y * bv.x; acc[1][1] += av.y * bv.y; acc[1][2] += av.y * bv.z; acc[1][3] += av.y * bv.w;
            acc[2][0] += av.z * bv.x; acc[2][1] += av.z * bv.y; acc[2][2] += av.z * bv.z; acc[2][3] += av.z * bv.w;
            acc[3][0] += av.w * bv.x; acc[3][1] += av.w * bv.y; acc[3][2] += av.w * bv.z; acc[3][3] += av.w * bv.w;
        }
        __syncthreads();
    }

    const float4 bv = *(const float4*)(bias + bn * TN + n0);
#pragma unroll
    for (int i = 0; i < 4; i++) {
        float4 v;
        v.x = acc[i][0] + bv.x;
        v.y = acc[i][1] + bv.y;
        v.z = acc[i][2] + bv.z;
        v.w = acc[i][3] + bv.w;
        *(float4*)&C[(size_t)(row0 + m0 + i) * N + bn * TN + n0] = v;
    }
}

// ---------------------------------------------------------------------------
// LSTM recurrence, L2-streamed U.
// One block per batch element. NT = 4*HN/CPT threads; thread owns CPT adjacent
// gate columns. U[k][col] streamed from L2 each step (all 64 blocks read the
// same 1 MB -> stays L2-resident). Chunked k-loop (CH=16) with depth-2 A/B
// prefetch; '#pragma unroll 1' keeps the compiler from hoisting all loads
// (round-1 spill disaster). h broadcast via LDS float4 reads.
// ---------------------------------------------------------------------------
__device__ __forceinline__ float fsig(float z) { return 1.f / (1.f + __expf(-z)); }
__device__ __forceinline__ float ftanh(float z) {
    const float e = __expf(2.f * z);
    return 1.f - 2.f / (e + 1.f);
}

template <int HN, int CPT>
__global__ __launch_bounds__(4 * HN / CPT) void lstm_rec_stream(
    const float* __restrict__ xz,   // [B, T, 4*HN]
    const float* __restrict__ U,    // [HN, 4*HN]
    float* __restrict__ hout,       // [B, T, HN] or nullptr
    float* __restrict__ out_last)   // [B, HN] or nullptr
{
    constexpr int GATES = 4 * HN;
    constexpr int CH = 16;          // k per chunk
    __shared__ __align__(16) float h_sh[HN];
    __shared__ __align__(16) float act_sh[GATES];

    const int tid = threadIdx.x;
    const int b = blockIdx.x;
    const int col = tid * CPT;
    const float* Ucol = U + col;
    const float* xzb = xz + (size_t)b * T_ * GATES + col;

    if (tid < HN) h_sh[tid] = 0.f;
    float c = 0.f;
    __syncthreads();

    // gate class is uniform across a thread's CPT adjacent columns
    const bool tanh_gate = (col >= 2 * HN) && (col < 3 * HN);

    for (int t = 0; t < T_; ++t) {
        float zp0[CPT], zp1[CPT];
#pragma unroll
        for (int cc = 0; cc < CPT; ++cc) {
            zp0[cc] = xzb[(size_t)t * GATES + cc];
            zp1[cc] = 0.f;
        }

        float uA[CH][CPT], uB[CH][CPT];

        auto loadChunk = [&](float (&dst)[CH][CPT], int kbase) {
#pragma unroll
            for (int j = 0; j < CH; ++j) {
                const float* p = Ucol + (size_t)(kbase + j) * GATES;
                if constexpr (CPT == 2) {
                    const float2 v = *(const float2*)p;
                    dst[j][0] = v.x; dst[j][1] = v.y;
                } else {
                    dst[j][0] = *p;
                }
            }
        };
        auto fmaChunk = [&](const float (&src)[CH][CPT], int kbase) {
#pragma unroll
            for (int j = 0; j < CH; j += 4) {
                const float4 h4 = *(const float4*)&h_sh[kbase + j];
#pragma unroll
                for (int cc = 0; cc < CPT; ++cc) {
                    zp0[cc] += h4.x * src[j + 0][cc];
                    zp1[cc] += h4.y * src[j + 1][cc];
                    zp0[cc] += h4.z * src[j + 2][cc];
                    zp1[cc] += h4.w * src[j + 3][cc];
                }
            }
        };

        loadChunk(uA, 0);
        loadChunk(uB, CH);
#pragma unroll 1
        for (int kk = 0; kk < HN; kk += 2 * CH) {
            fmaChunk(uA, kk);
            if (kk + 2 * CH < HN) loadChunk(uA, kk + 2 * CH);
            fmaChunk(uB, kk + CH);
            if (kk + 3 * CH < HN) loadChunk(uB, kk + 3 * CH);
        }

        float a[CPT];
#pragma unroll
        for (int cc = 0; cc < CPT; ++cc) {
            const float zz = zp0[cc] + zp1[cc];
            a[cc] = tanh_gate ? ftanh(zz) : fsig(zz);
        }
        if constexpr (CPT == 2) {
            *(float2*)&act_sh[col] = make_float2(a[0], a[1]);
        } else {
            act_sh[col] = a[0];
        }
        __syncthreads();

        if (tid < HN) {
            const float i_g = act_sh[tid];
            const float f_g = act_sh[HN + tid];
            const float g_g = act_sh[2 * HN + tid];
            const float o_g = act_sh[3 * HN + tid];
            c = f_g * c + i_g * g_g;
            const float h = o_g * ftanh(c);
            h_sh[tid] = h;
            if (hout) hout[((size_t)b * T_ + t) * HN + tid] = h;
            if (out_last && t == T_ - 1) out_last[(size_t)b * HN + tid] = h;
        }
        __syncthreads();
    }
}

// ---------------------------------------------------------------------------
// Launch
// ---------------------------------------------------------------------------
extern "C" void kernel_launch(void* const* d_in, const int* in_sizes, int n_in,
                              void* d_out, int out_size, void* d_ws, size_t ws_size,
                              hipStream_t stream)
{
    const float* x  = (const float*)d_in[0];
    const float* W0 = (const float*)d_in[1];
    const float* U0 = (const float*)d_in[2];
    const float* b0 = (const float*)d_in[3];
    const float* W1 = (const float*)d_in[4];
    const float* U1 = (const float*)d_in[5];
    const float* b1 = (const float*)d_in[6];
    const float* W2 = (const float*)d_in[7];
    const float* U2 = (const float*)d_in[8];
    const float* b2 = (const float*)d_in[9];
    const float* m0 = (const float*)d_in[10];
    const float* m1 = (const float*)d_in[11];
    const float* m2 = (const float*)d_in[12];
    float* out = (float*)d_out;

    // workspace layout (fp32):
    //   xz : 64*512*1024 floats = 134217728 B (reused by all 3 layers)
    //   h0 : 64*512*256 floats  =  33554432 B
    //   h1 : 64*512*256 floats  =  33554432 B
    float* xz = (float*)d_ws;
    float* h0 = (float*)((char*)d_ws + 134217728);
    float* h1 = (float*)((char*)d_ws + 134217728 + 33554432);

    const int M = B_ * T_;  // 32768

    // Layer 0
    gemm_mask_kernel<<<dim3(1024 / 64, M / 64), 256, 0, stream>>>(x, W0, b0, m0, xz, M, 1024, 128);
    lstm_rec_stream<256, 2><<<64, 512, 0, stream>>>(xz, U0, h0, nullptr);

    // Layer 1
    gemm_mask_kernel<<<dim3(1024 / 64, M / 64), 256, 0, stream>>>(h0, W1, b1, m1, xz, M, 1024, 256);
    lstm_rec_stream<256, 2><<<64, 512, 0, stream>>>(xz, U1, h1, nullptr);

    // Layer 2 (H=128), emit last h only
    gemm_mask_kernel<<<dim3(512 / 64, M / 64), 256, 0, stream>>>(h1, W2, b2, m2, xz, M, 512, 256);
    lstm_rec_stream<128, 1><<<64, 512, 0, stream>>>(xz, U2, nullptr, out);
}

// Round 3
// 15899.532 us; speedup vs baseline: 2.7268x; 1.0315x over previous
//
#include <hip/hip_runtime.h>
#include <math.h>

#define B_ 64
#define T_ 512

// ---------------------------------------------------------------------------
// GEMM: C[M,N] = (A[M,K] * mask[row/T_, :]) @ W[K,N] + bias[N]
// fp32, 64x64 tile, TK=32, 256 threads, 4x4 microtile per thread.
// ---------------------------------------------------------------------------
__global__ __launch_bounds__(256) void gemm_mask_kernel(
    const float* __restrict__ A, const float* __restrict__ W,
    const float* __restrict__ bias, const float* __restrict__ mask,
    float* __restrict__ C, int M, int N, int K)
{
    const int TM = 64, TN = 64, TK = 32;
    __shared__ __align__(16) float As[TK][68];
    __shared__ __align__(16) float Bs[TK][68];

    const int tid = threadIdx.x;
    const int bn = blockIdx.x;
    const int bm = blockIdx.y;
    const int row0 = bm * TM;
    const int b = row0 / T_;

    const int ty = tid >> 4;
    const int tx = tid & 15;
    const int m0 = ty * 4;
    const int n0 = tx * 4;

    float acc[4][4];
#pragma unroll
    for (int i = 0; i < 4; i++)
#pragma unroll
        for (int j = 0; j < 4; j++) acc[i][j] = 0.f;

    for (int kk = 0; kk < K; kk += TK) {
        {
            const int r = tid >> 3;
            const int kq = (tid & 7) << 2;
            const float4 mv = *(const float4*)(mask + (size_t)b * K + kk + kq);
#pragma unroll
            for (int rr = 0; rr < 2; rr++) {
                const int r2 = r + rr * 32;
                const float4 av = *(const float4*)(A + (size_t)(row0 + r2) * K + kk + kq);
                As[kq + 0][r2] = av.x * mv.x;
                As[kq + 1][r2] = av.y * mv.y;
                As[kq + 2][r2] = av.z * mv.z;
                As[kq + 3][r2] = av.w * mv.w;
            }
        }
        {
            const int kr = tid >> 4;
            const int nq = (tid & 15) << 2;
#pragma unroll
            for (int rr = 0; rr < 2; rr++) {
                const int k2 = kr + rr * 16;
                const float4 bv = *(const float4*)(W + (size_t)(kk + k2) * N + bn * TN + nq);
                *(float4*)&Bs[k2][nq] = bv;
            }
        }
        __syncthreads();

#pragma unroll
        for (int k = 0; k < TK; k++) {
            const float4 av = *(const float4*)&As[k][m0];
            const float4 bv = *(const float4*)&Bs[k][n0];
            acc[0][0] += av.x * bv.x; acc[0][1] += av.x * bv.y; acc[0][2] += av.x * bv.z; acc[0][3] += av.x * bv.w;
            acc[1][0] += av.y * bv.x; acc[1][1] += av.y * bv.y; acc[1][2] += av.y * bv.z; acc[1][3] += av.y * bv.w;
            acc[2][0] += av.z * bv.x; acc[2][1] += av.z * bv.y; acc[2][2] += av.z * bv.z; acc[2][3] += av.z * bv.w;
            acc[3][0] += av.w * bv.x; acc[3][1] += av.w * bv.y; acc[3][2] += av.w * bv.z; acc[3][3] += av.w * bv.w;
        }
        __syncthreads();
    }

    const float4 bv = *(const float4*)(bias + bn * TN + n0);
#pragma unroll
    for (int i = 0; i < 4; i++) {
        float4 v;
        v.x = acc[i][0] + bv.x;
        v.y = acc[i][1] + bv.y;
        v.z = acc[i][2] + bv.z;
        v.w = acc[i][3] + bv.w;
        *(float4*)&C[(size_t)(row0 + m0 + i) * N + bn * TN + n0] = v;
    }
}

// ---------------------------------------------------------------------------
// LSTM recurrence, register-resident U, 4 blocks per batch element.
// Block (b,q) owns hidden units j in [q*HB, (q+1)*HB), i.e. gate columns
// {g*HN + q*HB + j'} for g=0..3. U slice (HN k x HN cols) lives in VGPRs:
// 2*HN threads, thread owns one column-half (HN/2 k values = HN/2 VGPRs).
// Per step: FMA vs LDS-broadcast h, partner-combine via LDS, activations,
// 64-float h-slice exchange through global hbuf with device-scope
// release/acquire flags (double-buffered by step parity).
// ---------------------------------------------------------------------------
__device__ __forceinline__ float fsig(float z) { return 1.f / (1.f + __expf(-z)); }
__device__ __forceinline__ float ftanh(float z) {
    const float e = __expf(2.f * z);
    return 1.f - 2.f / (e + 1.f);
}

template <int HN>
__global__ __launch_bounds__(2 * HN, 2) void lstm_rec_sync(
    const float* __restrict__ xz,   // [B, T, 4*HN]
    const float* __restrict__ U,    // [HN, 4*HN]
    float* __restrict__ hout,       // [B, T, HN] or nullptr
    float* __restrict__ out_last,   // [B, HN] or nullptr
    float* __restrict__ hbuf,       // [2][B*HN] exchange buffer
    int* __restrict__ flags)        // [B*4], zeroed before launch
{
    constexpr int GATES = 4 * HN;
    constexpr int COLS = HN;        // gate columns per block
    constexpr int HB = HN / 4;      // hidden units per block
    constexpr int KH = HN / 2;      // k-range per thread

    __shared__ __align__(16) float h_sh[HN];
    __shared__ float zpart[COLS];
    __shared__ float act_sh[COLS];

    const int tid = threadIdx.x;
    const int blk = blockIdx.x;
    const int b = blk >> 2;
    const int q = blk & 3;

    const int c = (tid < COLS) ? tid : tid - COLS;   // local column
    const int khalf = (tid < COLS) ? 0 : 1;
    const int group = c / HB;                        // gate index 0..3
    const int within = c % HB;
    const int gcol = group * HN + q * HB + within;   // global gate column
    const int kbase = khalf * KH;

    // one-time: load U column-half into registers
    float u[KH];
#pragma unroll
    for (int kk = 0; kk < KH; ++kk)
        u[kk] = U[(size_t)(kbase + kk) * GATES + gcol];

    if (tid < HN) h_sh[tid] = 0.f;
    float cst = 0.f;
    __syncthreads();

    const float* xzb = xz + (size_t)b * T_ * GATES + gcol;
    const int fbase = b * 4;
    const bool tanh_gate = (group == 2);

    for (int t = 0; t < T_; ++t) {
        float z0 = 0.f;
        if (tid < COLS) z0 = xzb[(size_t)t * GATES];   // prefetch xz

        float zp = 0.f, zq = 0.f;
#pragma unroll
        for (int kk = 0; kk < KH; kk += 4) {
            const float4 h4 = *(const float4*)&h_sh[kbase + kk];
            zp += h4.x * u[kk + 0];
            zq += h4.y * u[kk + 1];
            zp += h4.z * u[kk + 2];
            zq += h4.w * u[kk + 3];
        }
        const float zsum = zp + zq;
        if (tid >= COLS) zpart[c] = zsum;
        __syncthreads();

        if (tid < COLS) {
            const float z = z0 + zsum + zpart[c];
            act_sh[c] = tanh_gate ? ftanh(z) : fsig(z);
        }
        __syncthreads();

        float hnew = 0.f;
        if (tid < HB) {
            const float ig = act_sh[tid];
            const float fg = act_sh[HB + tid];
            const float gg = act_sh[2 * HB + tid];
            const float og = act_sh[3 * HB + tid];
            cst = fg * cst + ig * gg;
            hnew = og * ftanh(cst);
            if (hout) hout[((size_t)b * T_ + t) * HN + q * HB + tid] = hnew;
            if (out_last && t == T_ - 1) out_last[(size_t)b * HN + q * HB + tid] = hnew;
        }

        if (t < T_ - 1) {
            const int s = t & 1;
            // publish own h slice (wave 0 only: HB <= 64)
            if (tid < HB)
                __hip_atomic_store(&hbuf[(size_t)s * B_ * HN + b * HN + q * HB + tid],
                                   hnew, __ATOMIC_RELAXED, __HIP_MEMORY_SCOPE_AGENT);
            if (tid == 0) {
                __threadfence();   // agent-scope fence: covers wave 0's stores
                __hip_atomic_store(&flags[fbase + q], t + 1,
                                   __ATOMIC_RELEASE, __HIP_MEMORY_SCOPE_AGENT);
            }
            // spin on all 4 sibling flags (lanes 0..3 of wave 0)
            if (tid < 4) {
                while (__hip_atomic_load(&flags[fbase + tid],
                                         __ATOMIC_ACQUIRE, __HIP_MEMORY_SCOPE_AGENT) < t + 1)
                    __builtin_amdgcn_s_sleep(1);
            }
            __syncthreads();
            // pull full h into LDS
            if (tid < HN)
                h_sh[tid] = __hip_atomic_load(&hbuf[(size_t)s * B_ * HN + b * HN + tid],
                                              __ATOMIC_RELAXED, __HIP_MEMORY_SCOPE_AGENT);
            __syncthreads();
        }
    }
}

// ---------------------------------------------------------------------------
// Launch
// ---------------------------------------------------------------------------
extern "C" void kernel_launch(void* const* d_in, const int* in_sizes, int n_in,
                              void* d_out, int out_size, void* d_ws, size_t ws_size,
                              hipStream_t stream)
{
    const float* x  = (const float*)d_in[0];
    const float* W0 = (const float*)d_in[1];
    const float* U0 = (const float*)d_in[2];
    const float* b0 = (const float*)d_in[3];
    const float* W1 = (const float*)d_in[4];
    const float* U1 = (const float*)d_in[5];
    const float* b1 = (const float*)d_in[6];
    const float* W2 = (const float*)d_in[7];
    const float* U2 = (const float*)d_in[8];
    const float* b2 = (const float*)d_in[9];
    const float* m0 = (const float*)d_in[10];
    const float* m1 = (const float*)d_in[11];
    const float* m2 = (const float*)d_in[12];
    float* out = (float*)d_out;

    // workspace layout (fp32):
    //   xz    : 134217728 B   (64*512*1024 floats, reused by all 3 layers)
    //   h0    :  33554432 B
    //   h1    :  33554432 B
    //   hbuf  :    131072 B   (2 x 64 x 256 floats, shared across layers)
    //   flags :      3072 B   (3 layers x 256 ints)
    char* ws = (char*)d_ws;
    float* xz   = (float*)ws;
    float* h0   = (float*)(ws + 134217728);
    float* h1   = (float*)(ws + 134217728 + 33554432);
    float* hbuf = (float*)(ws + 134217728 + 2 * 33554432);
    int*   flg  = (int*)  (ws + 134217728 + 2 * 33554432 + 131072);

    // flags must start at 0 every call (d_ws is poisoned 0xAA)
    hipMemsetAsync(flg, 0, 3 * 256 * sizeof(int), stream);

    const int M = B_ * T_;  // 32768

    // Layer 0
    gemm_mask_kernel<<<dim3(1024 / 64, M / 64), 256, 0, stream>>>(x, W0, b0, m0, xz, M, 1024, 128);
    lstm_rec_sync<256><<<256, 512, 0, stream>>>(xz, U0, h0, nullptr, hbuf, flg);

    // Layer 1
    gemm_mask_kernel<<<dim3(1024 / 64, M / 64), 256, 0, stream>>>(h0, W1, b1, m1, xz, M, 1024, 256);
    lstm_rec_sync<256><<<256, 512, 0, stream>>>(xz, U1, h1, nullptr, hbuf, flg + 256);

    // Layer 2 (H=128), emit last h only
    gemm_mask_kernel<<<dim3(512 / 64, M / 64), 256, 0, stream>>>(h1, W2, b2, m2, xz, M, 512, 256);
    lstm_rec_sync<128><<<256, 256, 0, stream>>>(xz, U2, nullptr, out, hbuf, flg + 512);
}

// Round 4
// 13983.885 us; speedup vs baseline: 3.1003x; 1.1370x over previous
//
#include <hip/hip_runtime.h>
#include <math.h>

#define B_ 64
#define T_ 512

// ---------------------------------------------------------------------------
// GEMM: C[M,N] = (A[M,K] * mask[row/T_, :]) @ W[K,N] + bias[N]
// fp32, 64x64 tile, TK=32, 256 threads, 4x4 microtile per thread.
// ---------------------------------------------------------------------------
__global__ __launch_bounds__(256) void gemm_mask_kernel(
    const float* __restrict__ A, const float* __restrict__ W,
    const float* __restrict__ bias, const float* __restrict__ mask,
    float* __restrict__ C, int M, int N, int K)
{
    const int TM = 64, TN = 64, TK = 32;
    __shared__ __align__(16) float As[TK][68];
    __shared__ __align__(16) float Bs[TK][68];

    const int tid = threadIdx.x;
    const int bn = blockIdx.x;
    const int bm = blockIdx.y;
    const int row0 = bm * TM;
    const int b = row0 / T_;

    const int ty = tid >> 4;
    const int tx = tid & 15;
    const int m0 = ty * 4;
    const int n0 = tx * 4;

    float acc[4][4];
#pragma unroll
    for (int i = 0; i < 4; i++)
#pragma unroll
        for (int j = 0; j < 4; j++) acc[i][j] = 0.f;

    for (int kk = 0; kk < K; kk += TK) {
        {
            const int r = tid >> 3;
            const int kq = (tid & 7) << 2;
            const float4 mv = *(const float4*)(mask + (size_t)b * K + kk + kq);
#pragma unroll
            for (int rr = 0; rr < 2; rr++) {
                const int r2 = r + rr * 32;
                const float4 av = *(const float4*)(A + (size_t)(row0 + r2) * K + kk + kq);
                As[kq + 0][r2] = av.x * mv.x;
                As[kq + 1][r2] = av.y * mv.y;
                As[kq + 2][r2] = av.z * mv.z;
                As[kq + 3][r2] = av.w * mv.w;
            }
        }
        {
            const int kr = tid >> 4;
            const int nq = (tid & 15) << 2;
#pragma unroll
            for (int rr = 0; rr < 2; rr++) {
                const int k2 = kr + rr * 16;
                const float4 bv = *(const float4*)(W + (size_t)(kk + k2) * N + bn * TN + nq);
                *(float4*)&Bs[k2][nq] = bv;
            }
        }
        __syncthreads();

#pragma unroll
        for (int k = 0; k < TK; k++) {
            const float4 av = *(const float4*)&As[k][m0];
            const float4 bv = *(const float4*)&Bs[k][n0];
            acc[0][0] += av.x * bv.x; acc[0][1] += av.x * bv.y; acc[0][2] += av.x * bv.z; acc[0][3] += av.x * bv.w;
            acc[1][0] += av.y * bv.x; acc[1][1] += av.y * bv.y; acc[1][2] += av.y * bv.z; acc[1][3] += av.y * bv.w;
            acc[2][0] += av.z * bv.x; acc[2][1] += av.z * bv.y; acc[2][2] += av.z * bv.z; acc[2][3] += av.z * bv.w;
            acc[3][0] += av.w * bv.x; acc[3][1] += av.w * bv.y; acc[3][2] += av.w * bv.z; acc[3][3] += av.w * bv.w;
        }
        __syncthreads();
    }

    const float4 bv = *(const float4*)(bias + bn * TN + n0);
#pragma unroll
    for (int i = 0; i < 4; i++) {
        float4 v;
        v.x = acc[i][0] + bv.x;
        v.y = acc[i][1] + bv.y;
        v.z = acc[i][2] + bv.z;
        v.w = acc[i][3] + bv.w;
        *(float4*)&C[(size_t)(row0 + m0 + i) * N + bn * TN + n0] = v;
    }
}

// ---------------------------------------------------------------------------
// LSTM recurrence v4: register-resident U, 4 blocks per batch element.
// Block (q,b) at blockIdx = q*64 + b (XCD swizzle: all 4 siblings of batch b
// land on XCD b%8 under round-robin dispatch). Block owns hidden units
// [q*HB, (q+1)*HB) -> COLS=HN gate columns. Thread = (kq, cp): owns gate
// columns {2cp, 2cp+1} (local) x k-quarter kq, i.e. float2 u2[KH] in VGPRs.
// amdgpu_waves_per_eu(2,2) pins the register budget to 256 so the allocator
// does NOT spill the array (round-1/round-3 failure mode).
// Per step: FMA vs LDS-broadcast h (wave-uniform b128 reads), 4-way k
// reduction via LDS, activations, cell update, 4-block h exchange through
// global hbuf with agent-scope release/acquire flags (parity double-buffer).
// ---------------------------------------------------------------------------
__device__ __forceinline__ float fsig(float z) { return 1.f / (1.f + __expf(-z)); }
__device__ __forceinline__ float ftanh(float z) {
    const float e = __expf(2.f * z);
    return 1.f - 2.f / (e + 1.f);
}

template <int HN>
__global__ __launch_bounds__(2 * HN)
__attribute__((amdgpu_waves_per_eu(2, 2)))
void lstm_rec_v4(
    const float* __restrict__ xz,   // [B, T, 4*HN]
    const float* __restrict__ U,    // [HN, 4*HN]
    float* __restrict__ hout,       // [B, T, HN] or nullptr
    float* __restrict__ out_last,   // [B, HN] or nullptr
    float* __restrict__ hbuf,       // [2][B_*HN] exchange buffer
    int* __restrict__ flags)        // [B_*4], zeroed before launch
{
    constexpr int GATES = 4 * HN;
    constexpr int COLS = HN;        // gate columns per block
    constexpr int CP = COLS / 2;    // column-pairs per block
    constexpr int HB = HN / 4;      // hidden units per block
    constexpr int KH = HN / 4;      // k-range per thread (4 k-quarters)

    __shared__ __align__(16) float h_sh[HN];
    __shared__ __align__(16) float2 zpart[3 * CP];
    __shared__ __align__(16) float act_sh[COLS];

    const int tid = threadIdx.x;
    const int q = blockIdx.x >> 6;          // quarter 0..3
    const int b = blockIdx.x & 63;          // batch element

    const int cp = tid % CP;                // column-pair
    const int kq = tid / CP;                // k-quarter (wave-uniform)
    const int c0 = 2 * cp;                  // local col
    const int group = c0 / HB;              // gate 0..3 (both cols same gate)
    const int within = c0 % HB;
    const int gcol = group * HN + q * HB + within;   // global gate column
    const int kbase = kq * KH;

    // one-time: U fragment (KH k x 2 cols) into registers
    float2 u2[KH];
#pragma unroll
    for (int j = 0; j < KH; ++j)
        u2[j] = *(const float2*)&U[(size_t)(kbase + j) * GATES + gcol];

    if (tid < HN) h_sh[tid] = 0.f;
    float cst = 0.f;
    __syncthreads();

    const float* xzb = xz + (size_t)b * T_ * GATES + gcol;
    const int fbase = b * 4;
    const bool tanh_gate = (group == 2);

#pragma unroll 1
    for (int t = 0; t < T_; ++t) {
        float2 z0;
        if (kq == 0) z0 = *(const float2*)(xzb + (size_t)t * GATES);  // prefetch xz

        float2 za = make_float2(0.f, 0.f), zb = make_float2(0.f, 0.f);
#pragma unroll
        for (int j = 0; j < KH; j += 4) {
            const float4 h4 = *(const float4*)&h_sh[kbase + j];   // wave-uniform bcast
            za.x += h4.x * u2[j + 0].x; za.y += h4.x * u2[j + 0].y;
            zb.x += h4.y * u2[j + 1].x; zb.y += h4.y * u2[j + 1].y;
            za.x += h4.z * u2[j + 2].x; za.y += h4.z * u2[j + 2].y;
            zb.x += h4.w * u2[j + 3].x; zb.y += h4.w * u2[j + 3].y;
        }
        const float2 zsum = make_float2(za.x + zb.x, za.y + zb.y);
        if (kq != 0) zpart[(kq - 1) * CP + cp] = zsum;
        __syncthreads();

        if (kq == 0) {
            const float2 p0 = zpart[cp];
            const float2 p1 = zpart[CP + cp];
            const float2 p2 = zpart[2 * CP + cp];
            const float zx = z0.x + zsum.x + p0.x + p1.x + p2.x;
            const float zy = z0.y + zsum.y + p0.y + p1.y + p2.y;
            float ax, ay;
            if (tanh_gate) { ax = ftanh(zx); ay = ftanh(zy); }
            else           { ax = fsig(zx);  ay = fsig(zy);  }
            *(float2*)&act_sh[c0] = make_float2(ax, ay);
        }
        __syncthreads();

        float hnew = 0.f;
        if (tid < HB) {
            const float ig = act_sh[tid];
            const float fg = act_sh[HB + tid];
            const float gg = act_sh[2 * HB + tid];
            const float og = act_sh[3 * HB + tid];
            cst = fg * cst + ig * gg;
            hnew = og * ftanh(cst);
            if (hout) hout[((size_t)b * T_ + t) * HN + q * HB + tid] = hnew;
            if (out_last && t == T_ - 1) out_last[(size_t)b * HN + q * HB + tid] = hnew;
        }

        if (t < T_ - 1) {
            const int s = t & 1;
            // publish own h slice (wave 0 only: HB <= 64)
            if (tid < HB)
                __hip_atomic_store(&hbuf[(size_t)s * B_ * HN + b * HN + q * HB + tid],
                                   hnew, __ATOMIC_RELAXED, __HIP_MEMORY_SCOPE_AGENT);
            if (tid == 0) {
                __threadfence();   // agent-scope fence covers wave 0's stores
                __hip_atomic_store(&flags[fbase + q], t + 1,
                                   __ATOMIC_RELEASE, __HIP_MEMORY_SCOPE_AGENT);
            }
            // spin on all 4 sibling flags (lanes 0..3 of wave 0)
            if (tid < 4) {
                while (__hip_atomic_load(&flags[fbase + tid],
                                         __ATOMIC_ACQUIRE, __HIP_MEMORY_SCOPE_AGENT) < t + 1)
                    __builtin_amdgcn_s_sleep(1);
            }
            __syncthreads();
            // pull full h into LDS (wave 0, float4 coalesced; ordered after
            // the acquire above, published to other waves by the barrier)
            if (tid < HN / 4) {
                const float4 hv = *(const float4*)&hbuf[(size_t)s * B_ * HN + b * HN + 4 * tid];
                *(float4*)&h_sh[4 * tid] = hv;
            }
            __syncthreads();
        }
    }
}

// ---------------------------------------------------------------------------
// Launch
// ---------------------------------------------------------------------------
extern "C" void kernel_launch(void* const* d_in, const int* in_sizes, int n_in,
                              void* d_out, int out_size, void* d_ws, size_t ws_size,
                              hipStream_t stream)
{
    const float* x  = (const float*)d_in[0];
    const float* W0 = (const float*)d_in[1];
    const float* U0 = (const float*)d_in[2];
    const float* b0 = (const float*)d_in[3];
    const float* W1 = (const float*)d_in[4];
    const float* U1 = (const float*)d_in[5];
    const float* b1 = (const float*)d_in[6];
    const float* W2 = (const float*)d_in[7];
    const float* U2 = (const float*)d_in[8];
    const float* b2 = (const float*)d_in[9];
    const float* m0 = (const float*)d_in[10];
    const float* m1 = (const float*)d_in[11];
    const float* m2 = (const float*)d_in[12];
    float* out = (float*)d_out;

    // workspace layout (fp32):
    //   xz    : 134217728 B   (64*512*1024 floats, reused by all 3 layers)
    //   h0    :  33554432 B
    //   h1    :  33554432 B
    //   hbuf  :    131072 B   (2 x 64 x 256 floats, shared across layers)
    //   flags :      3072 B   (3 layers x 256 ints)
    char* ws = (char*)d_ws;
    float* xz   = (float*)ws;
    float* h0   = (float*)(ws + 134217728);
    float* h1   = (float*)(ws + 134217728 + 33554432);
    float* hbuf = (float*)(ws + 134217728 + 2 * 33554432);
    int*   flg  = (int*)  (ws + 134217728 + 2 * 33554432 + 131072);

    // flags must start at 0 every call (d_ws is poisoned 0xAA)
    hipMemsetAsync(flg, 0, 3 * 256 * sizeof(int), stream);

    const int M = B_ * T_;  // 32768

    // Layer 0
    gemm_mask_kernel<<<dim3(1024 / 64, M / 64), 256, 0, stream>>>(x, W0, b0, m0, xz, M, 1024, 128);
    lstm_rec_v4<256><<<256, 512, 0, stream>>>(xz, U0, h0, nullptr, hbuf, flg);

    // Layer 1
    gemm_mask_kernel<<<dim3(1024 / 64, M / 64), 256, 0, stream>>>(h0, W1, b1, m1, xz, M, 1024, 256);
    lstm_rec_v4<256><<<256, 512, 0, stream>>>(xz, U1, h1, nullptr, hbuf, flg + 256);

    // Layer 2 (H=128), emit last h only
    gemm_mask_kernel<<<dim3(512 / 64, M / 64), 256, 0, stream>>>(h1, W2, b2, m2, xz, M, 512, 256);
    lstm_rec_v4<128><<<256, 256, 0, stream>>>(xz, U2, nullptr, out, hbuf, flg + 512);
}